// Round 1
// baseline (63771.173 us; speedup 1.0000x reference)
//
#include <hip/hip_runtime.h>
#include <math.h>

#define Bq 64
#define Tq 512
#define Iq 1024
#define Hq 1024
#define G4 4096  /* 4*H */

// ---------------------------------------------------------------------------
// xproj GEMM: xproj[M=B*T=32768, 4096] = x[M,1024] @ Wx[1024,4096]
// tile 64x64, K-tile 16, 256 threads, micro 4x4, LDS pad 68 (float4-aligned,
// 2-way-max bank aliasing which is free on gfx950)
// ---------------------------------------------------------------------------
__global__ __launch_bounds__(256) void xproj_gemm(const float* __restrict__ x,
                                                  const float* __restrict__ Wx,
                                                  float* __restrict__ xproj) {
    __shared__ float As[16][68];
    __shared__ float Bs[16][68];
    const int m0 = blockIdx.y * 64;
    const int n0 = blockIdx.x * 64;
    const int tid = threadIdx.x;
    const int tm = tid & 15, tn = tid >> 4;
    float acc[4][4] = {};
    for (int k0 = 0; k0 < Iq; k0 += 16) {
#pragma unroll
        for (int e = 0; e < 4; ++e) {
            int flat = e * 256 + tid;
            int k = flat & 15, m = flat >> 4;
            As[k][m] = x[(size_t)(m0 + m) * Iq + k0 + k];
        }
#pragma unroll
        for (int e = 0; e < 4; ++e) {
            int flat = e * 256 + tid;
            int n = flat & 63, k = flat >> 6;
            Bs[k][n] = Wx[(size_t)(k0 + k) * G4 + n0 + n];
        }
        __syncthreads();
#pragma unroll
        for (int k = 0; k < 16; ++k) {
            float4 a = *(const float4*)&As[k][tm * 4];
            float4 b = *(const float4*)&Bs[k][tn * 4];
            acc[0][0] += a.x * b.x; acc[0][1] += a.x * b.y; acc[0][2] += a.x * b.z; acc[0][3] += a.x * b.w;
            acc[1][0] += a.y * b.x; acc[1][1] += a.y * b.y; acc[1][2] += a.y * b.z; acc[1][3] += a.y * b.w;
            acc[2][0] += a.z * b.x; acc[2][1] += a.z * b.y; acc[2][2] += a.z * b.z; acc[2][3] += a.z * b.w;
            acc[3][0] += a.w * b.x; acc[3][1] += a.w * b.y; acc[3][2] += a.w * b.z; acc[3][3] += a.w * b.w;
        }
        __syncthreads();
    }
#pragma unroll
    for (int i = 0; i < 4; ++i) {
        int row = m0 + tm * 4 + i;
        float4 v = make_float4(acc[i][0], acc[i][1], acc[i][2], acc[i][3]);
        *(float4*)&xproj[(size_t)row * G4 + n0 + tn * 4] = v;
    }
}

// ---------------------------------------------------------------------------
// step gates GEMM: gates[64,4096] = h_prev[64,1024] @ Wh[1024,4096] (+ xproj_t)
// or, if fused (no xproj scratch), additionally + x_t[64,1024] @ Wx (K=2048).
// M-tile 32, N-tile 32, K-tile 32, 256 threads, micro 2x2. Grid (128,2).
// ---------------------------------------------------------------------------
__global__ __launch_bounds__(256) void step_gates(const float* __restrict__ h_prev,
                                                  const float* __restrict__ Wh,
                                                  const float* __restrict__ xproj,
                                                  const float* __restrict__ x,
                                                  const float* __restrict__ Wx,
                                                  int t, int fused,
                                                  float* __restrict__ gates) {
    __shared__ float As[32][34];
    __shared__ float Bs[32][34];
    const int n0 = blockIdx.x * 32;
    const int m0 = blockIdx.y * 32;
    const int tid = threadIdx.x;
    const int tm = tid & 15, tn = tid >> 4;
    float acc[2][2] = {};
    const int KT = fused ? (Hq + Iq) : Hq;
    for (int k0 = 0; k0 < KT; k0 += 32) {
#pragma unroll
        for (int e = 0; e < 4; ++e) {
            int flat = e * 256 + tid;
            int k = flat & 31, m = flat >> 5;
            int kk = k0 + k;
            float v;
            if (kk < Hq) {
                v = h_prev[(size_t)(m0 + m) * Hq + kk];
            } else {
                v = x[((size_t)(m0 + m) * Tq + t) * Iq + (kk - Hq)];
            }
            As[k][m] = v;
        }
#pragma unroll
        for (int e = 0; e < 4; ++e) {
            int flat = e * 256 + tid;
            int n = flat & 31, k = flat >> 5;
            int kk = k0 + k;
            const float* Brow = (kk < Hq) ? &Wh[(size_t)kk * G4] : &Wx[(size_t)(kk - Hq) * G4];
            Bs[k][n] = Brow[n0 + n];
        }
        __syncthreads();
#pragma unroll
        for (int k = 0; k < 32; ++k) {
            float2 a = *(const float2*)&As[k][tm * 2];
            float2 b = *(const float2*)&Bs[k][tn * 2];
            acc[0][0] += a.x * b.x; acc[0][1] += a.x * b.y;
            acc[1][0] += a.y * b.x; acc[1][1] += a.y * b.y;
        }
        __syncthreads();
    }
#pragma unroll
    for (int i = 0; i < 2; ++i) {
        int m = m0 + tm * 2 + i;
        int col = n0 + tn * 2;
        float2 v = make_float2(acc[i][0], acc[i][1]);
        if (xproj) {
            float2 xp = *(const float2*)&xproj[((size_t)m * Tq + t) * G4 + col];
            v.x += xp.x; v.y += xp.y;
        }
        *(float2*)&gates[(size_t)m * G4 + col] = v;
    }
}

// ---------------------------------------------------------------------------
// pointwise LSTM cell update: activations, c update, h write (ping-pong),
// and store h into out[b, t, :].
// ---------------------------------------------------------------------------
__global__ __launch_bounds__(256) void step_update(const float* __restrict__ gates,
                                                   const float* __restrict__ bias,
                                                   float* __restrict__ c,
                                                   float* __restrict__ h_next,
                                                   float* __restrict__ out, int t) {
    int idx = blockIdx.x * 256 + threadIdx.x;  // 0..65535
    int b = idx >> 10, j = idx & 1023;
    size_t base = (size_t)b * G4;
    float gi = gates[base + j] + bias[j];
    float gf = gates[base + Hq + j] + bias[Hq + j];
    float gg = gates[base + 2 * Hq + j] + bias[2 * Hq + j];
    float go = gates[base + 3 * Hq + j] + bias[3 * Hq + j];
    float i_ = 1.0f / (1.0f + expf(-gi));
    float f_ = 1.0f / (1.0f + expf(-gf));
    float g_ = tanhf(gg);
    float o_ = 1.0f / (1.0f + expf(-go));
    float cn = f_ * c[idx] + i_ * g_;
    c[idx] = cn;
    float hn = o_ * tanhf(cn);
    h_next[idx] = hn;
    out[((size_t)b * Tq + t) * Hq + j] = hn;
}

extern "C" void kernel_launch(void* const* d_in, const int* in_sizes, int n_in,
                              void* d_out, int out_size, void* d_ws, size_t ws_size,
                              hipStream_t stream) {
    const float* x    = (const float*)d_in[0];
    const float* Wx   = (const float*)d_in[1];
    const float* Wh   = (const float*)d_in[2];
    const float* bias = (const float*)d_in[3];
    float* out = (float*)d_out;
    float* ws = (float*)d_ws;

    // ws layout (floats): c[65536] | h0[65536] | h1[65536] | gates[262144] | xproj[32768*4096]
    float* c     = ws;
    float* h0    = ws + 65536;
    float* h1    = ws + 131072;
    float* gates = ws + 196608;
    float* xproj = ws + 458752;
    const size_t need_pre = (458752ull + (size_t)32768 * 4096) * 4ull;
    const int precompute = (ws_size >= need_pre) ? 1 : 0;

    // zero initial h and c (ws is poisoned 0xAA before every call)
    hipMemsetAsync(c, 0, 65536 * sizeof(float), stream);
    hipMemsetAsync(h0, 0, 65536 * sizeof(float), stream);

    if (precompute) {
        dim3 grid(G4 / 64, (Bq * Tq) / 64);  // (64, 512)
        xproj_gemm<<<grid, 256, 0, stream>>>(x, Wx, xproj);
    }

    float* hbuf[2] = {h0, h1};
    for (int t = 0; t < Tq; ++t) {
        dim3 grid(G4 / 32, Bq / 32);  // (128, 2)
        step_gates<<<grid, 256, 0, stream>>>(hbuf[t & 1], Wh,
                                             precompute ? xproj : nullptr,
                                             x, Wx, t, precompute ? 0 : 1, gates);
        step_update<<<Bq * Hq / 256, 256, 0, stream>>>(gates, bias, c,
                                                       hbuf[(t + 1) & 1], out, t);
    }
}

// Round 2
// 24482.097 us; speedup vs baseline: 2.6048x; 2.6048x over previous
//
#include <hip/hip_runtime.h>
#include <math.h>

#define Bq 64
#define Tq 512
#define Hq 1024
#define G4 4096
#define NBLK 256
#define NTHR 512

typedef __attribute__((ext_vector_type(8))) short short8;   // 8 bf16
typedef __attribute__((ext_vector_type(4))) float float4v;  // MFMA acc

static __device__ __forceinline__ short f2bf(float f) {
    union { float f; unsigned u; } c; c.f = f;
    unsigned r = (c.u + 0x7fffu + ((c.u >> 16) & 1u)) >> 16;  // RNE
    return (short)r;
}

static __device__ __forceinline__ short8 load_cvt8(const float* p) {
    const float4* q = (const float4*)p;  // p is 32B-aligned by construction
    float4 v0 = q[0], v1 = q[1];
    short8 r;
    r[0] = f2bf(v0.x); r[1] = f2bf(v0.y); r[2] = f2bf(v0.z); r[3] = f2bf(v0.w);
    r[4] = f2bf(v1.x); r[5] = f2bf(v1.y); r[6] = f2bf(v1.z); r[7] = f2bf(v1.w);
    return r;
}

// ---------------------------------------------------------------------------
// Persistent LSTM kernel.
// Grid: 256 blocks (4 mc x 64 jc) x 512 threads (8 waves).
// Block owns output tile: rows = batch mc*16..+15, j = jc*16..+15 (x4 gates =
// 64 gate-cols, as 4 MFMA N-tiles of 16).
// Waves 0..3: K-chunk of h (256 each); waves 4..7: K-chunk of x_t (256 each).
// B fragments (bf16) live in registers for the whole time loop (32 frags/wave).
// Cell state c lives in registers of threads 0..255. Grid barrier per step.
// ---------------------------------------------------------------------------
__global__ __launch_bounds__(NTHR, 2) void lstm_persist(
        const float* __restrict__ x, const float* __restrict__ Wx,
        const float* __restrict__ Wh, const float* __restrict__ bias,
        float* __restrict__ out, float* __restrict__ h0, float* __restrict__ h1,
        unsigned* __restrict__ flags)
{
    __shared__ float part[8][16][64];   // per-wave partial gate tiles (32 KB)
    __shared__ float gtile[16][64];     // reduced gates (4 KB)
    __shared__ float sbias[64];

    const int tid  = threadIdx.x;
    const int w    = tid >> 6;
    const int lane = tid & 63;
    const int blk  = blockIdx.x;
    const int mc   = blk >> 6;    // 0..3   batch-row group
    const int jc   = blk & 63;    // 0..63  j group (16 j's)
    const int quad = lane >> 4;   // 0..3
    const int n    = lane & 15;   // MFMA col within tile
    const int gN   = n >> 2;      // gate index for B cols
    const int jl4  = n & 3;

    if (tid < 64) {
        int u = tid >> 4, nn = tid & 15;
        sbias[u * 16 + nn] = bias[(nn >> 2) * Hq + jc * 16 + u * 4 + (nn & 3)];
    }

    // ---- one-time: load B fragments (bf16) into registers -----------------
    // virtual K = [ h (0..1023) | x (1024..2047) ]; wave w owns [w*256, w*256+256)
    short8 bs[4][8];  // [N-tile u][k-step s]
    const int kchunk = w * 256;
#pragma unroll
    for (int u = 0; u < 4; ++u) {
        const int col = gN * Hq + jc * 16 + u * 4 + jl4;
#pragma unroll
        for (int s = 0; s < 8; ++s) {
            const int kb = kchunk + s * 32 + quad * 8;
#pragma unroll
            for (int j = 0; j < 8; ++j) {
                const int kv = kb + j;
                float v = (kv < Hq) ? Wh[(size_t)kv * G4 + col]
                                    : Wx[(size_t)(kv - Hq) * G4 + col];
                bs[u][s][j] = f2bf(v);
            }
        }
    }

    // cell state for this thread's (row, j) — threads 0..255
    float cstate = 0.f;
    const int urow = tid >> 4;   // 0..15 (valid when tid<256)
    const int ujl  = tid & 15;   // j within block's 16

    const int m_g = mc * 16 + n;  // A row (batch) for this lane
    const float* xbase = x + (size_t)m_g * Tq * Hq +
                         ((w >= 4) ? (w - 4) * 256 + quad * 8 : 0);
    const size_t hoff = (size_t)m_g * Hq + (size_t)(w * 256) + quad * 8;

    for (int t = 0; t < Tq; ++t) {
        const float* hprev = (t & 1) ? h1 : h0;
        float*       hnext = (t & 1) ? h0 : h1;

        float4v acc0 = {0,0,0,0}, acc1 = {0,0,0,0}, acc2 = {0,0,0,0}, acc3 = {0,0,0,0};
        if (w < 4) {
            const float* ap = hprev + hoff;
#pragma unroll
            for (int s = 0; s < 8; ++s) {
                short8 a = load_cvt8(ap + s * 32);
                acc0 = __builtin_amdgcn_mfma_f32_16x16x32_bf16(a, bs[0][s], acc0, 0, 0, 0);
                acc1 = __builtin_amdgcn_mfma_f32_16x16x32_bf16(a, bs[1][s], acc1, 0, 0, 0);
                acc2 = __builtin_amdgcn_mfma_f32_16x16x32_bf16(a, bs[2][s], acc2, 0, 0, 0);
                acc3 = __builtin_amdgcn_mfma_f32_16x16x32_bf16(a, bs[3][s], acc3, 0, 0, 0);
            }
        } else {
            const float* ap = xbase + (size_t)t * Hq;
#pragma unroll
            for (int s = 0; s < 8; ++s) {
                short8 a = load_cvt8(ap + s * 32);
                acc0 = __builtin_amdgcn_mfma_f32_16x16x32_bf16(a, bs[0][s], acc0, 0, 0, 0);
                acc1 = __builtin_amdgcn_mfma_f32_16x16x32_bf16(a, bs[1][s], acc1, 0, 0, 0);
                acc2 = __builtin_amdgcn_mfma_f32_16x16x32_bf16(a, bs[2][s], acc2, 0, 0, 0);
                acc3 = __builtin_amdgcn_mfma_f32_16x16x32_bf16(a, bs[3][s], acc3, 0, 0, 0);
            }
        }
#pragma unroll
        for (int r = 0; r < 4; ++r) {
            part[w][quad * 4 + r][ 0 + n] = acc0[r];
            part[w][quad * 4 + r][16 + n] = acc1[r];
            part[w][quad * 4 + r][32 + n] = acc2[r];
            part[w][quad * 4 + r][48 + n] = acc3[r];
        }
        __syncthreads();

        // reduce 8 partials -> gates (1024 values, 2 per thread)
#pragma unroll
        for (int e = 0; e < 2; ++e) {
            int idx = tid + e * NTHR;
            int rr = idx >> 6, cc = idx & 63;
            float s = part[0][rr][cc];
#pragma unroll
            for (int ww = 1; ww < 8; ++ww) s += part[ww][rr][cc];
            gtile[rr][cc] = s + sbias[cc];
        }
        __syncthreads();

        if (tid < 256) {
            // column layout in gtile: cc = u*16 + g*4 + jl4 ; j = jc*16 + u*4 + jl4
            const int u = ujl >> 2, j4 = ujl & 3;
            float gi = gtile[urow][u * 16 +  0 + j4];
            float gf = gtile[urow][u * 16 +  4 + j4];
            float gg = gtile[urow][u * 16 +  8 + j4];
            float go = gtile[urow][u * 16 + 12 + j4];
            float i_ = 1.f / (1.f + __expf(-gi));
            float f_ = 1.f / (1.f + __expf(-gf));
            float g_ = tanhf(gg);
            float o_ = 1.f / (1.f + __expf(-go));
            cstate = f_ * cstate + i_ * g_;
            float hn = o_ * tanhf(cstate);
            const int bg = mc * 16 + urow;
            const int jg = jc * 16 + ujl;
            hnext[(size_t)bg * Hq + jg] = hn;
            out[((size_t)bg * Tq + t) * Hq + jg] = hn;
        }
        __syncthreads();  // h writes drained (barrier implies vmcnt(0))

        // ---- grid barrier: all-to-all flags ----
        if (tid == 0) {
            __threadfence();  // L2 writeback, device scope
            __hip_atomic_store(&flags[blk], (unsigned)(t + 1),
                               __ATOMIC_RELEASE, __HIP_MEMORY_SCOPE_AGENT);
        }
        if (tid < NBLK) {
            while (__hip_atomic_load(&flags[tid], __ATOMIC_RELAXED,
                                     __HIP_MEMORY_SCOPE_AGENT) < (unsigned)(t + 1)) {}
        }
        __threadfence();  // acquire: invalidate stale L1/L2 before next h reads
        __syncthreads();
    }
}

extern "C" void kernel_launch(void* const* d_in, const int* in_sizes, int n_in,
                              void* d_out, int out_size, void* d_ws, size_t ws_size,
                              hipStream_t stream) {
    const float* x    = (const float*)d_in[0];
    const float* Wx   = (const float*)d_in[1];
    const float* Wh   = (const float*)d_in[2];
    const float* bias = (const float*)d_in[3];
    float* out = (float*)d_out;

    // ws layout: flags[256] u32 (1 KB) | h0[64*1024] f32 | h1[64*1024] f32
    unsigned* flags = (unsigned*)d_ws;
    float* h0 = (float*)((char*)d_ws + 1024);
    float* h1 = h0 + Bq * Hq;

    // zero flags + h0 (ws is re-poisoned 0xAA before every timed call)
    hipMemsetAsync(d_ws, 0, 1024 + (size_t)Bq * Hq * sizeof(float), stream);

    void* args[] = {(void*)&x, (void*)&Wx, (void*)&Wh, (void*)&bias,
                    (void*)&out, (void*)&h0, (void*)&h1, (void*)&flags};
    hipLaunchCooperativeKernel((const void*)lstm_persist, dim3(NBLK), dim3(NTHR),
                               args, 0, stream);
}

// Round 3
// 7706.853 us; speedup vs baseline: 8.2746x; 3.1767x over previous
//
#include <hip/hip_runtime.h>
#include <math.h>

#define Bq 64
#define Tq 512
#define Hq 1024
#define G4 4096
#define NBLK 256
#define NTHR 512

typedef __attribute__((ext_vector_type(8))) short short8;   // 8 bf16
typedef __attribute__((ext_vector_type(4))) float float4v;  // MFMA acc

static __device__ __forceinline__ short f2bf(float f) {
    union { float f; unsigned u; } c; c.f = f;
    unsigned r = (c.u + 0x7fffu + ((c.u >> 16) & 1u)) >> 16;  // RNE
    return (short)r;
}

static __device__ __forceinline__ short8 load_cvt8(const float* p) {
    const float4* q = (const float4*)p;  // 32B-aligned by construction
    float4 v0 = q[0], v1 = q[1];
    short8 r;
    r[0] = f2bf(v0.x); r[1] = f2bf(v0.y); r[2] = f2bf(v0.z); r[3] = f2bf(v0.w);
    r[4] = f2bf(v1.x); r[5] = f2bf(v1.y); r[6] = f2bf(v1.z); r[7] = f2bf(v1.w);
    return r;
}

// agent-scope relaxed atomic helpers (lower to sc0 sc1 cache-bypass ops; no fences)
static __device__ __forceinline__ float aload_f(const float* p) {
    return __hip_atomic_load(p, __ATOMIC_RELAXED, __HIP_MEMORY_SCOPE_AGENT);
}
static __device__ __forceinline__ void astore_f(float* p, float v) {
    __hip_atomic_store(p, v, __ATOMIC_RELAXED, __HIP_MEMORY_SCOPE_AGENT);
}
static __device__ __forceinline__ unsigned aload_u(const unsigned* p) {
    return __hip_atomic_load(p, __ATOMIC_RELAXED, __HIP_MEMORY_SCOPE_AGENT);
}
static __device__ __forceinline__ void astore_u(unsigned* p, unsigned v) {
    __hip_atomic_store(p, v, __ATOMIC_RELAXED, __HIP_MEMORY_SCOPE_AGENT);
}

// ---------------------------------------------------------------------------
// Persistent LSTM kernel.
// Grid: 256 blocks (4 mc x 64 jc) x 512 threads (8 waves).
// Block owns output tile: rows = batch mc*16..+15, j = jc*16..+15 (x4 gates).
// Waves 0..3: K-chunk of h (256 each); waves 4..7: K-chunk of x_t (256 each).
// B fragments (bf16) live in registers for the whole time loop.
// Cell state c lives in registers of threads 0..255.
// All cross-block traffic (h, flags) via relaxed agent atomics — NO fences.
// ---------------------------------------------------------------------------
__global__ __launch_bounds__(NTHR, 2) void lstm_persist(
        const float* __restrict__ x, const float* __restrict__ Wx,
        const float* __restrict__ Wh, const float* __restrict__ bias,
        float* __restrict__ out, float* __restrict__ h0, float* __restrict__ h1,
        unsigned* __restrict__ flags)
{
    __shared__ float part[8][16][64];   // per-wave partial gate tiles (32 KB)
    __shared__ float gtile[16][64];     // reduced gates (4 KB)
    __shared__ float sbias[64];

    const int tid  = threadIdx.x;
    const int w    = tid >> 6;
    const int lane = tid & 63;
    const int blk  = blockIdx.x;
    const int mc   = blk >> 6;    // 0..3   batch-row group
    const int jc   = blk & 63;    // 0..63  j group (16 j's)
    const int quad = lane >> 4;   // 0..3
    const int n    = lane & 15;   // MFMA col within tile
    const int gN   = n >> 2;      // gate index for B cols
    const int jl4  = n & 3;

    if (tid < 64) {
        int u = tid >> 4, nn = tid & 15;
        sbias[u * 16 + nn] = bias[(nn >> 2) * Hq + jc * 16 + u * 4 + (nn & 3)];
    }

    // ---- one-time: load B fragments (bf16) into registers -----------------
    // virtual K = [ h (0..1023) | x (1024..2047) ]; wave w owns [w*256, +256)
    short8 bs[4][8];  // [N-tile u][k-step s]
    const int kchunk = w * 256;
#pragma unroll
    for (int u = 0; u < 4; ++u) {
        const int col = gN * Hq + jc * 16 + u * 4 + jl4;
#pragma unroll
        for (int s = 0; s < 8; ++s) {
            const int kb = kchunk + s * 32 + quad * 8;
#pragma unroll
            for (int j = 0; j < 8; ++j) {
                const int kv = kb + j;
                float v = (kv < Hq) ? Wh[(size_t)kv * G4 + col]
                                    : Wx[(size_t)(kv - Hq) * G4 + col];
                bs[u][s][j] = f2bf(v);
            }
        }
    }

    float cstate = 0.f;          // cell state (threads 0..255)
    const int urow = tid >> 4;   // 0..15 (valid when tid<256)
    const int ujl  = tid & 15;

    const int m_g = mc * 16 + n;  // A row (batch) for this lane
    const float* xbase = x + (size_t)m_g * Tq * Hq +
                         ((w >= 4) ? (w - 4) * 256 + quad * 8 : 0);
    const size_t hoff = (size_t)m_g * Hq + (size_t)(w * 256) + quad * 8;

    for (int t = 0; t < Tq; ++t) {
        const float* hprev = (t & 1) ? h1 : h0;
        float*       hnext = (t & 1) ? h0 : h1;

        float4v acc0 = {0,0,0,0}, acc1 = {0,0,0,0}, acc2 = {0,0,0,0}, acc3 = {0,0,0,0};
        if (w < 4) {
            if (t > 0) {  // h == 0 at t==0
                const float* ap = hprev + hoff;
#pragma unroll
                for (int s = 0; s < 8; ++s) {
                    short8 a;
#pragma unroll
                    for (int j = 0; j < 8; ++j)
                        a[j] = f2bf(aload_f(ap + s * 32 + j));
                    acc0 = __builtin_amdgcn_mfma_f32_16x16x32_bf16(a, bs[0][s], acc0, 0, 0, 0);
                    acc1 = __builtin_amdgcn_mfma_f32_16x16x32_bf16(a, bs[1][s], acc1, 0, 0, 0);
                    acc2 = __builtin_amdgcn_mfma_f32_16x16x32_bf16(a, bs[2][s], acc2, 0, 0, 0);
                    acc3 = __builtin_amdgcn_mfma_f32_16x16x32_bf16(a, bs[3][s], acc3, 0, 0, 0);
                }
            }
        } else {
            const float* ap = xbase + (size_t)t * Hq;
#pragma unroll
            for (int s = 0; s < 8; ++s) {
                short8 a = load_cvt8(ap + s * 32);
                acc0 = __builtin_amdgcn_mfma_f32_16x16x32_bf16(a, bs[0][s], acc0, 0, 0, 0);
                acc1 = __builtin_amdgcn_mfma_f32_16x16x32_bf16(a, bs[1][s], acc1, 0, 0, 0);
                acc2 = __builtin_amdgcn_mfma_f32_16x16x32_bf16(a, bs[2][s], acc2, 0, 0, 0);
                acc3 = __builtin_amdgcn_mfma_f32_16x16x32_bf16(a, bs[3][s], acc3, 0, 0, 0);
            }
        }
#pragma unroll
        for (int r = 0; r < 4; ++r) {
            part[w][quad * 4 + r][ 0 + n] = acc0[r];
            part[w][quad * 4 + r][16 + n] = acc1[r];
            part[w][quad * 4 + r][32 + n] = acc2[r];
            part[w][quad * 4 + r][48 + n] = acc3[r];
        }
        __syncthreads();

        // reduce 8 partials -> gates (1024 values, 2 per thread)
#pragma unroll
        for (int e = 0; e < 2; ++e) {
            int idx = tid + e * NTHR;
            int rr = idx >> 6, cc = idx & 63;
            float s = part[0][rr][cc];
#pragma unroll
            for (int ww = 1; ww < 8; ++ww) s += part[ww][rr][cc];
            gtile[rr][cc] = s + sbias[cc];
        }
        __syncthreads();

        float hn = 0.f;
        int bg = 0, jg = 0;
        if (tid < 256) {
            const int u = ujl >> 2, j4 = ujl & 3;
            float gi = gtile[urow][u * 16 +  0 + j4];
            float gf = gtile[urow][u * 16 +  4 + j4];
            float gg = gtile[urow][u * 16 +  8 + j4];
            float go = gtile[urow][u * 16 + 12 + j4];
            float i_ = 1.f / (1.f + __expf(-gi));
            float f_ = 1.f / (1.f + __expf(-gf));
            float g_ = tanhf(gg);
            float o_ = 1.f / (1.f + __expf(-go));
            cstate = f_ * cstate + i_ * g_;
            hn = o_ * tanhf(cstate);
            bg = mc * 16 + urow;
            jg = jc * 16 + ujl;
            astore_f(&hnext[(size_t)bg * Hq + jg], hn);  // cache-bypass store
        }
        __syncthreads();  // vmcnt(0): all h stores acked at coherence point

        if (tid == 0) astore_u(&flags[blk], (unsigned)(t + 1));

        // out store is NOT on the critical path — after the flag post
        if (tid < 256) out[((size_t)bg * Tq + t) * Hq + jg] = hn;

        // ---- grid barrier: only wave 0 polls (64 lanes x 4 flags) ----
        if (w == 0) {
            const unsigned tgt = (unsigned)(t + 1);
            for (;;) {
                unsigned a0 = aload_u(&flags[lane]);
                unsigned a1 = aload_u(&flags[lane + 64]);
                unsigned a2 = aload_u(&flags[lane + 128]);
                unsigned a3 = aload_u(&flags[lane + 192]);
                bool ok = (a0 >= tgt) && (a1 >= tgt) && (a2 >= tgt) && (a3 >= tgt);
                if (__all(ok)) break;
            }
        }
        __syncthreads();
    }
}

extern "C" void kernel_launch(void* const* d_in, const int* in_sizes, int n_in,
                              void* d_out, int out_size, void* d_ws, size_t ws_size,
                              hipStream_t stream) {
    const float* x    = (const float*)d_in[0];
    const float* Wx   = (const float*)d_in[1];
    const float* Wh   = (const float*)d_in[2];
    const float* bias = (const float*)d_in[3];
    float* out = (float*)d_out;

    // ws layout: flags[256] u32 (1 KB) | h0[64*1024] f32 | h1[64*1024] f32
    unsigned* flags = (unsigned*)d_ws;
    float* h0 = (float*)((char*)d_ws + 1024);
    float* h1 = h0 + Bq * Hq;

    // zero flags (h0 never read at t=0; kernel skips the h-MFMA there)
    hipMemsetAsync(d_ws, 0, 1024, stream);

    void* args[] = {(void*)&x, (void*)&Wx, (void*)&Wh, (void*)&bias,
                    (void*)&out, (void*)&h0, (void*)&h1, (void*)&flags};
    hipLaunchCooperativeKernel((const void*)lstm_persist, dim3(NBLK), dim3(NTHR),
                               args, 0, stream);
}